// Round 9
// baseline (20.832 us; speedup 1.0000x reference)
//
#include <hip/hip_runtime.h>
#include <hip/hip_fp16.h>

#define NB   8
#define NDEP 64
#define KK   512
#define NP   12
#define NT   550
#define BWIN 40                    // per-bn tick band [floor(z)-20, +20)
#define L2E  1.4426950408889634f

// ws table layout (dwords):
//  [0..27]    w1a  = W1[0][j]*L2E
//  [28..55]   w1b  = W1[1][j]*L2E
//  [56..83]   b1s  = b1[j]*L2E
//  [84..251]  w2pk = half2(W2[j][2c], W2[j][2c+1])   (j*6+c)
//  [252..257] b2pk = half2(b2[2c], b2[2c+1])
//  [258..269] qtab = pscale[p]^2 * GAUSS_NORM

static __device__ __forceinline__ float fast_rcp(float x) {
    return __builtin_amdgcn_rcpf(x);
}
static __device__ __forceinline__ unsigned packh2(float a, float b) {
    __half2 h = __floats2half2_rn(a, b);
    return __builtin_bit_cast(unsigned, h);
}

__global__ __launch_bounds__(256) void init_kernel(
    const float* __restrict__ W1, const float* __restrict__ b1,
    const float* __restrict__ W2, const float* __restrict__ b2,
    const float* __restrict__ pscale,
    float* __restrict__ ws, float* __restrict__ out, int out_size)
{
    const int idx = blockIdx.x * 256 + threadIdx.x;
    for (int i = idx; i < out_size; i += gridDim.x * 256) out[i] = 0.0f;

    if (blockIdx.x == 0) {
        const int t = threadIdx.x;
        if (t < 28) {
            ws[t]      = W1[t]      * L2E;
            ws[28 + t] = W1[28 + t] * L2E;
            ws[56 + t] = b1[t]      * L2E;
        }
        if (t >= 64 && t < 232) {              // 168 packed W2 entries
            const int e = t - 64, j = e / 6, c = e - j * 6;
            ((unsigned*)(ws + 84))[e] = packh2(W2[j * NP + 2 * c], W2[j * NP + 2 * c + 1]);
        }
        if (t >= 232 && t < 238) {
            const int c = t - 232;
            ((unsigned*)(ws + 252))[c] = packh2(b2[2 * c], b2[2 * c + 1]);
        }
        if (t >= 238 && t < 250) {
            const int p = t - 238;
            ws[258 + p] = pscale[p] * pscale[p] * 3.9894228040143274f;
        }
    }
}

// LDS row k at dword offset k*16 + (k>>4)*4 (16B pad per 16 rows): the S
// concurrent sub reads land on distinct bank groups.
// Gather over this wave's 64 rows; park totals in part[(off+tw)*12 ..].
template<int S>
static __device__ __forceinline__ void gather_partial(
    const float* __restrict__ wl, int lane, int t_lo, int off,
    float* __restrict__ ppart)
{
    constexpr int W = 64 / S;
    const int tw  = lane & (W - 1);
    const int sub = lane / W;
    const float tc = (float)t_lo + (float)tw + 0.5f;

    float acc[NP];
    #pragma unroll
    for (int p = 0; p < NP; ++p) acc[p] = 0.0f;

    #pragma unroll 4
    for (int i = 0; i < W; ++i) {
        const int k = sub * W + i;
        const int o = (k << 4) + ((k >> 4) << 2);
        const float4 r0 = *(const float4*)&wl[o];
        const float4 r1 = *(const float4*)&wl[o + 4];
        const float4 r2 = *(const float4*)&wl[o + 8];
        const float ez  = wl[o + 12];
        const float d   = tc - ez;
        const float g   = exp2f(-14.426950408889634f * d * d);   // exp(-10 d^2)
        acc[0]  = fmaf(r0.x, g, acc[0]);  acc[1]  = fmaf(r0.y, g, acc[1]);
        acc[2]  = fmaf(r0.z, g, acc[2]);  acc[3]  = fmaf(r0.w, g, acc[3]);
        acc[4]  = fmaf(r1.x, g, acc[4]);  acc[5]  = fmaf(r1.y, g, acc[5]);
        acc[6]  = fmaf(r1.z, g, acc[6]);  acc[7]  = fmaf(r1.w, g, acc[7]);
        acc[8]  = fmaf(r2.x, g, acc[8]);  acc[9]  = fmaf(r2.y, g, acc[9]);
        acc[10] = fmaf(r2.z, g, acc[10]); acc[11] = fmaf(r2.w, g, acc[11]);
    }

    #pragma unroll
    for (int msk = W; msk < 64; msk <<= 1) {
        #pragma unroll
        for (int p = 0; p < NP; ++p) acc[p] += __shfl_xor(acc[p], msk);
    }

    if (lane < W) {
        float* pp = ppart + (size_t)(off + lane) * NP;   // 48B-aligned
        *(float4*)&pp[0] = make_float4(acc[0], acc[1],  acc[2],  acc[3]);
        *(float4*)&pp[4] = make_float4(acc[4], acc[5],  acc[6],  acc[7]);
        *(float4*)&pp[8] = make_float4(acc[8], acc[9],  acc[10], acc[11]);
    }
}

__global__ __launch_bounds__(512) void next_sim_wave(
    const float* __restrict__ ed,      // (8,64,4) x,y,z,E
    const float* __restrict__ edraw,   // (8,64)
    const float* __restrict__ ddraw,   // (8,64,512,3)
    const float* __restrict__ udraw,   // (8,64,512)
    const float* __restrict__ wst,     // packed weight table (ws)
    const float* __restrict__ dscale, const float* __restrict__ life,
    float* __restrict__ out)           // (8,12,550)
{
    __shared__ float rows[8][1040];        // per-wave private f32 rows (33.3 KB)
    __shared__ float part[8][BWIN * NP];   // per-wave window partials (15.4 KB)
    __shared__ int2  hdr[8];               // {off_in_band, W} per wave

    const int tid  = threadIdx.x;
    const int lane = tid & 63;
    const int wid  = tid >> 6;
    const int bn   = blockIdx.x;           // 512 blocks: one per (b,n)
    const int b    = bn >> 6;

    // ---- hoisted loads: all independent, issue before any math
    const float4 dep = ((const float4*)ed)[bn];
    const float  edr = edraw[bn];
    const int    k   = (wid << 6) + lane;
    const float* dd  = ddraw + ((size_t)bn * KK + k) * 3;
    const float d0 = dd[0], d1 = dd[1], d2 = dd[2];
    const float u  = udraw[(size_t)bn * KK + k];

    // ---- wave-uniform header
    const float nval  = dep.w * (1000000.0f / 22.4f);
    const float sigma = sqrtf(0.15f * nval);
    int ne = (int)(sigma * edr + nval);    // trunc == astype(int32)
    ne = min(max(ne, 0), KK);
    const int tb = (int)floorf(dep.z) - BWIN / 2;   // band start, in [30,479]
    const bool walive = ((wid << 6) < ne);

    if (walive) {
        const float sqz     = sqrtf(dep.z);
        const float invLife = fast_rcp(life[0]);
        const float dS0 = dscale[0] * dscale[0];
        const float dS1 = dscale[1] * dscale[1];
        const float dS2 = dscale[2] * dscale[2];

        const float ez = fmaf(dS2 * d2, sqz, dep.z);
        const float ex = fmaf(dS0 * d0, sqz, dep.x);
        const float ey = fmaf(dS1 * d1, sqz, dep.y);
        const float prob = 1.0f - __expf(-ez * invLife);
        const float m = ((k < ne) && (prob > u)) ? 1.0f : 0.0f;

        // MLP: hidden f32 (pre-scaled weights -> exp2), output layer packed f16
        const float*   w1a  = wst;
        const float*   w1b  = wst + 28;
        const float*   b1s  = wst + 56;
        const __half2* w2pk = (const __half2*)(wst + 84);
        const __half2* b2pk = (const __half2*)(wst + 252);
        const float*   qtab = wst + 258;

        __half2 pa0 = b2pk[0], pa1 = b2pk[1], pa2 = b2pk[2];
        __half2 pa3 = b2pk[3], pa4 = b2pk[4], pa5 = b2pk[5];
        #pragma unroll 4
        for (int j = 0; j < 28; ++j) {
            const float lg  = fmaf(w1a[j], ex, fmaf(w1b[j], ey, b1s[j]));
            const float hjf = fast_rcp(1.0f + exp2f(-lg));
            const __half2 h2 = __float2half2_rn(hjf);
            pa0 = __hfma2(h2, w2pk[j * 6 + 0], pa0);
            pa1 = __hfma2(h2, w2pk[j * 6 + 1], pa1);
            pa2 = __hfma2(h2, w2pk[j * 6 + 2], pa2);
            pa3 = __hfma2(h2, w2pk[j * 6 + 3], pa3);
            pa4 = __hfma2(h2, w2pk[j * 6 + 4], pa4);
            pa5 = __hfma2(h2, w2pk[j * 6 + 5], pa5);
        }
        float pm[NP];
        { float2 f;
          f = __half22float2(pa0); pm[0] = f.x; pm[1] = f.y;
          f = __half22float2(pa1); pm[2] = f.x; pm[3] = f.y;
          f = __half22float2(pa2); pm[4] = f.x; pm[5] = f.y;
          f = __half22float2(pa3); pm[6] = f.x; pm[7] = f.y;
          f = __half22float2(pa4); pm[8] = f.x; pm[9] = f.y;
          f = __half22float2(pa5); pm[10] = f.x; pm[11] = f.y; }

        float q[NP];
        #pragma unroll
        for (int p = 0; p < NP; ++p)
            q[p] = qtab[p] * m * fast_rcp(1.0f + exp2f(-pm[p] * L2E));

        // this lane's f32 row into the wave-private LDS region
        float* wl = rows[wid];
        const int off = (lane << 4) + ((lane >> 4) << 2);
        *(float4*)&wl[off]     = make_float4(q[0], q[1],  q[2],  q[3]);
        *(float4*)&wl[off + 4] = make_float4(q[4], q[5],  q[6],  q[7]);
        *(float4*)&wl[off + 8] = make_float4(q[8], q[9],  q[10], q[11]);
        wl[off + 12] = ez;

        // wave ez min/max -> adaptive sub-window inside the 40-tick band
        float ezmin = ez, ezmax = ez;
        #pragma unroll
        for (int msk = 1; msk < 64; msk <<= 1) {
            ezmin = fminf(ezmin, __shfl_xor(ezmin, msk));
            ezmax = fmaxf(ezmax, __shfl_xor(ezmax, msk));
        }
        const int fmin = (int)floorf(ezmin);
        const int fmax = (int)floorf(ezmax);
        const int need = fmax - fmin + 7;

        if (need <= 16) {
            const int t_lo = min(max(fmin - 3, tb), tb + BWIN - 16);
            gather_partial<4>(wl, lane, t_lo, t_lo - tb, part[wid]);
            if (lane == 0) hdr[wid] = make_int2(t_lo - tb, 16);
        } else {
            const int t_lo = min(max(fmin - 3, tb), tb + BWIN - 32);
            gather_partial<2>(wl, lane, t_lo, t_lo - tb, part[wid]);
            if (lane == 0) hdr[wid] = make_int2(t_lo - tb, 32);
        }
    } else {
        if (lane == 0) hdr[wid] = make_int2(0, 0);
    }
    __syncthreads();

    // ---- block combine: 480 threads, one (t_rel, p) each; one atomic per nonzero
    if (tid < BWIN * NP) {
        const int t_rel = tid / NP;
        const int p     = tid - t_rel * NP;
        float s = 0.0f;
        #pragma unroll
        for (int w = 0; w < 8; ++w) {
            const int2 h  = hdr[w];
            const int  dt = t_rel - h.x;
            if ((unsigned)dt < (unsigned)h.y)
                s += part[w][t_rel * NP + p];
        }
        if (s != 0.0f)
            atomicAdd(&out[((size_t)b * NP + p) * NT + (tb + t_rel)], s);
    }
}

extern "C" void kernel_launch(void* const* d_in, const int* in_sizes, int n_in,
                              void* d_out, int out_size, void* d_ws, size_t ws_size,
                              hipStream_t stream) {
    const float* ed     = (const float*)d_in[0];
    const float* edraw  = (const float*)d_in[1];
    const float* ddraw  = (const float*)d_in[2];
    const float* udraw  = (const float*)d_in[3];
    const float* W1     = (const float*)d_in[4];
    const float* b1     = (const float*)d_in[5];
    const float* W2     = (const float*)d_in[6];
    const float* b2     = (const float*)d_in[7];
    const float* dscale = (const float*)d_in[8];
    const float* pscale = (const float*)d_in[9];
    const float* life   = (const float*)d_in[10];
    float* ws  = (float*)d_ws;
    float* out = (float*)d_out;

    init_kernel<<<64, 256, 0, stream>>>(W1, b1, W2, b2, pscale, ws, out, out_size);
    next_sim_wave<<<NB * NDEP, 512, 0, stream>>>(
        ed, edraw, ddraw, udraw, ws, dscale, life, out);
}